// Round 7
// baseline (241.448 us; speedup 1.0000x reference)
//
#include <hip/hip_runtime.h>
#include <cstdint>
#include <cstddef>

#define EPSV 1e-5f
constexpr int B_ = 8;
constexpr int C_ = 512;
constexpr int N_ = 2048;

typedef _Float16 f16x8 __attribute__((ext_vector_type(8)));
typedef float    f32x4 __attribute__((ext_vector_type(4)));

__device__ __forceinline__ unsigned short f16b(float f) {
    _Float16 h = (_Float16)f;
    return __builtin_bit_cast(unsigned short, h);
}

__device__ __forceinline__ void gload_lds16(const void* g, void* l) {
    __builtin_amdgcn_global_load_lds(
        (const __attribute__((address_space(1))) void*)g,
        (__attribute__((address_space(3))) void*)l, 16, 0, 0);
}

// ---------------------------------------------------------------------------
// x (B,C,N) fp32 -> xT (B,N,C) fp16 (transposed so all GEMMs are K-contig)
// ---------------------------------------------------------------------------
__global__ __launch_bounds__(256) void split_x_kernel(
    const float* __restrict__ x, unsigned short* __restrict__ xh)
{
    __shared__ float T[64][65];
    const int b = blockIdx.z, c0 = blockIdx.y * 64, n0 = blockIdx.x * 64;
    const float* xb = x + ((size_t)b * C_ + c0) * N_ + n0;
    const int tid = threadIdx.x;
    const int lr = tid >> 4;
    const int lcn = (tid & 15) * 4;
#pragma unroll
    for (int it = 0; it < 4; ++it) {
        float4 v = *(const float4*)&xb[(size_t)(lr + 16 * it) * N_ + lcn];
        T[lr + 16 * it][lcn + 0] = v.x;
        T[lr + 16 * it][lcn + 1] = v.y;
        T[lr + 16 * it][lcn + 2] = v.z;
        T[lr + 16 * it][lcn + 3] = v.w;
    }
    __syncthreads();
    const int n = tid >> 2, cb = (tid & 3) * 16;
    alignas(16) unsigned short h[16];
#pragma unroll
    for (int i = 0; i < 16; ++i)
        h[i] = f16b(T[cb + i][n]);
    const size_t o = ((size_t)b * N_ + n0 + n) * C_ + c0 + cb;
    *(uint4*)&xh[o]     = *(uint4*)&h[0];
    *(uint4*)&xh[o + 8] = *(uint4*)&h[8];
}

// ---------------------------------------------------------------------------
// W (512x512) fp32 -> fp16
// ---------------------------------------------------------------------------
__global__ __launch_bounds__(256) void split_w_kernel(
    const float* __restrict__ W, unsigned short* __restrict__ wh)
{
    const int i = (blockIdx.x * 256 + threadIdx.x) * 4;
    float4 v = *(const float4*)&W[i];
    alignas(8) unsigned short h[4];
    h[0] = f16b(v.x); h[1] = f16b(v.y); h[2] = f16b(v.z); h[3] = f16b(v.w);
    *(ushort4*)&wh[i] = *(ushort4*)&h[0];
}

// ---------------------------------------------------------------------------
// MFMA GEMM (fp16 in, fp32 acc): C = A * B^T.  m97 structure, 128x128 tile.
// EPI_QK:   grid (256,1,B) with XCD-chunked swizzle (each XCD owns a 4x8
//           tile region -> k/q panels L2-resident).  Writes
//           p_local = exp(w - m_tile) fp16 (coalesced via LDS repack) and
//           per-64-col-tile stats (m_t, l_t) to ML.
// EPI_PV:   A-fragments scaled by corr[b,t,i] (t = k0/64) via packed-f16 mul,
//           epilogue * linv[i]; fp32 out at [n*M+m] (d-major)
// EPI_PROJT/PROJV: fused BN, fp16 out at [n*M+m]
// ---------------------------------------------------------------------------
constexpr int EPI_QK = 0, EPI_PV = 1, EPI_PROJT = 2, EPI_PROJV = 3;

template <int EPI>
__global__ __launch_bounds__(256) void gemm_mfma(
    const unsigned short* __restrict__ Ah, const unsigned short* __restrict__ Bh,
    int M, int N, int K, int lda, int ldb,
    long strideA, long strideB, long strideC,
    void* __restrict__ C0, float* __restrict__ ML,
    const float* __restrict__ corr, const float* __restrict__ linv,
    const float* __restrict__ g, const float* __restrict__ bt,
    const float* __restrict__ mu, const float* __restrict__ var)
{
    // QK needs 128x136 fp16 repack tile (34816 B); others 16 KiB.
    __shared__ char smem[(EPI == EPI_QK) ? 34816 : 16384];

    const int bz = blockIdx.z;
    const unsigned short* Ahb = Ah + (size_t)bz * strideA;
    const unsigned short* Bhb = Bh + (size_t)bz * strideB;

    int bx, by;
    if constexpr (EPI == EPI_QK) {
        // XCD-chunked swizzle: xcd = linear%8 owns bx in [cx*4,cx*4+4),
        // by in [cy*8,cy*8+8)  (cx=xcd&3, cy=xcd>>2).
        const int id = blockIdx.x;
        const int xcd = id & 7, s = id >> 3;
        bx = (xcd & 3) * 4 + (s & 3);
        by = (xcd >> 2) * 8 + (s >> 2);
    } else {
        bx = blockIdx.x;
        by = blockIdx.y;
    }
    const int n0 = bx * 128;
    const int m0 = by * 128;

    const int tid = threadIdx.x;
    const int lane = tid & 63;
    const int wv = tid >> 6;
    const int wr = wv >> 1, wc = wv & 1;
    const int l4 = lane >> 4, l15 = lane & 15;
    const int srow = lane >> 2, scol8 = (lane & 3) * 8;

    f32x4 acc[4][4] = {};
    float ca[4];                       // EPI_PV: per-fm corr for current tile

    for (int k0 = 0; k0 < K; k0 += 32) {
        if constexpr (EPI == EPI_PV) {
            if ((k0 & 63) == 0) {
                const int t = k0 >> 6;
                const float* cb = corr + ((size_t)bz * 32 + t) * 2048 + m0;
#pragma unroll
                for (int f = 0; f < 4; ++f)
                    ca[f] = cb[wr * 64 + f * 16 + l15];
            }
        }
#pragma unroll
        for (int cc = 0; cc < 2; ++cc) {
            const int c = wv * 2 + cc;
            const size_t aoff = (size_t)(m0 + c * 16 + srow) * lda + k0 + scol8;
            const size_t boff = (size_t)(n0 + c * 16 + srow) * ldb + k0 + scol8;
            gload_lds16(Ahb + aoff, smem + c * 1024);
            gload_lds16(Bhb + boff, smem + 8192 + c * 1024);
        }
        __syncthreads();

        f16x8 ah[4], bh[4];
#pragma unroll
        for (int f = 0; f < 4; ++f) {
            const int arow = wr * 64 + f * 16 + l15;
            const int brow = wc * 64 + f * 16 + l15;
            ah[f] = *(const f16x8*)(smem + arow * 64 + l4 * 16);
            bh[f] = *(const f16x8*)(smem + 8192 + brow * 64 + l4 * 16);
        }
        if constexpr (EPI == EPI_PV) {
#pragma unroll
            for (int f = 0; f < 4; ++f) {
                const _Float16 cf = (_Float16)ca[f];
                ah[f] = ah[f] * cf;        // packed v_pk_mul_f16
            }
        }
#pragma unroll
        for (int fm = 0; fm < 4; ++fm)
#pragma unroll
            for (int fn = 0; fn < 4; ++fn)
                acc[fm][fn] = __builtin_amdgcn_mfma_f32_16x16x32_f16(
                    ah[fm], bh[fn], acc[fm][fn], 0, 0, 0);
        __syncthreads();
    }

    if constexpr (EPI == EPI_QK) {
        // stats + exp into LDS repack tile, then coalesced 16B stores.
        unsigned short* H = (unsigned short*)C0 + (size_t)bz * strideC;
        unsigned short* pl = (unsigned short*)smem;      // [128][136] fp16
        const size_t mbase =
            (((size_t)bz * 32 + bx * 2 + wc) * 2) * 2048;
#pragma unroll
        for (int fm = 0; fm < 4; ++fm) {
#pragma unroll
            for (int r = 0; r < 4; ++r) {
                float mx = fmaxf(fmaxf(acc[fm][0][r], acc[fm][1][r]),
                                 fmaxf(acc[fm][2][r], acc[fm][3][r]));
#pragma unroll
                for (int off = 1; off < 16; off <<= 1)
                    mx = fmaxf(mx, __shfl_xor(mx, off));
                float pe[4];
                float s = 0.f;
#pragma unroll
                for (int fn = 0; fn < 4; ++fn) {
                    pe[fn] = __expf(acc[fm][fn][r] - mx);
                    s += pe[fn];
                }
#pragma unroll
                for (int off = 1; off < 16; off <<= 1)
                    s += __shfl_xor(s, off);
                const int rloc = wr * 64 + fm * 16 + l4 * 4 + r;
                if (l15 == 0) {
                    ML[mbase + m0 + rloc] = mx;
                    ML[mbase + 2048 + m0 + rloc] = s;
                }
#pragma unroll
                for (int fn = 0; fn < 4; ++fn)
                    pl[rloc * 136 + wc * 64 + fn * 16 + l15] = f16b(pe[fn]);
            }
        }
        __syncthreads();
#pragma unroll
        for (int it = 0; it < 8; ++it) {
            const int rr = (tid >> 4) + it * 16;
            const int cc8 = (tid & 15) * 8;
            *(uint4*)&H[(size_t)(m0 + rr) * N + n0 + cc8] =
                *(const uint4*)&pl[rr * 136 + cc8];
        }
    } else if constexpr (EPI == EPI_PV) {
        float* Cb = (float*)C0 + (size_t)bz * strideC;
        const float* lb = linv + (size_t)bz * 2048;
        float lv[4][4];
#pragma unroll
        for (int fm = 0; fm < 4; ++fm)
#pragma unroll
            for (int r = 0; r < 4; ++r)
                lv[fm][r] = lb[m0 + wr * 64 + fm * 16 + l4 * 4 + r];
#pragma unroll
        for (int fm = 0; fm < 4; ++fm)
#pragma unroll
            for (int fn = 0; fn < 4; ++fn) {
                const int m = m0 + wr * 64 + fm * 16 + l4 * 4;
                const int n = n0 + wc * 64 + fn * 16 + l15;
                float4 o4 = make_float4(acc[fm][fn][0] * lv[fm][0],
                                        acc[fm][fn][1] * lv[fm][1],
                                        acc[fm][fn][2] * lv[fm][2],
                                        acc[fm][fn][3] * lv[fm][3]);
                *(float4*)&Cb[(size_t)n * M + m] = o4;
            }
    } else {
#pragma unroll
        for (int fm = 0; fm < 4; ++fm) {
#pragma unroll
            for (int fn = 0; fn < 4; ++fn) {
                const int m = m0 + wr * 64 + fm * 16 + l4 * 4;
                const int n = n0 + wc * 64 + fn * 16 + l15;
                unsigned short* H = (unsigned short*)C0 + (size_t)bz * strideC;
                alignas(8) unsigned short h4[4];
                if constexpr (EPI == EPI_PROJT) {
#pragma unroll
                    for (int r = 0; r < 4; ++r) {
                        const int o = m + r;
                        const float sc = g[o] * rsqrtf(var[o] + EPSV);
                        const float sh = bt[o] - mu[o] * sc;
                        h4[r] = f16b(acc[fm][fn][r] * sc + sh);
                    }
                } else {  // EPI_PROJV
                    const float sc = g[n] * rsqrtf(var[n] + EPSV);
                    const float sh = bt[n] - mu[n] * sc;
#pragma unroll
                    for (int r = 0; r < 4; ++r)
                        h4[r] = f16b(acc[fm][fn][r] * sc + sh);
                }
                *(ushort4*)&H[(size_t)n * M + m] = *(ushort4*)&h4[0];
            }
        }
    }
}

// ---------------------------------------------------------------------------
// Combine 32 per-tile (m,l) partials: m_global, linv = 1/l_global, and
// corr[b,t,i] = exp(m_t - m_global).  One thread per (b, i).
// ---------------------------------------------------------------------------
__global__ __launch_bounds__(256) void ml_combine_kernel(
    const float* __restrict__ ml, float* __restrict__ corr,
    float* __restrict__ linv)
{
    const int idx = blockIdx.x * 256 + threadIdx.x;   // b*2048 + i
    const int b = idx >> 11, i = idx & 2047;
    const float* base = ml + ((size_t)b * 32) * 2 * 2048 + i;
    float M = -3.0e38f;
#pragma unroll 8
    for (int t = 0; t < 32; ++t)
        M = fmaxf(M, base[(size_t)t * 4096]);
    float L = 0.f;
    float* cb = corr + (size_t)b * 32 * 2048 + i;
#pragma unroll 8
    for (int t = 0; t < 32; ++t) {
        const float c = __expf(base[(size_t)t * 4096] - M);
        L += c * base[(size_t)t * 4096 + 2048];
        cb[(size_t)t * 2048] = c;
    }
    linv[idx] = 1.0f / L;
}

// ---------------------------------------------------------------------------
extern "C" void kernel_launch(void* const* d_in, const int* in_sizes, int n_in,
                              void* d_out, int out_size, void* d_ws, size_t ws_size,
                              hipStream_t stream)
{
    (void)in_sizes; (void)n_in; (void)out_size; (void)ws_size;
    const float* x  = (const float*)d_in[0];
    const float* Wq = (const float*)d_in[1];
    const float* gq = (const float*)d_in[2];
    const float* bq = (const float*)d_in[3];
    const float* mq = (const float*)d_in[4];
    const float* vq = (const float*)d_in[5];
    const float* Wk = (const float*)d_in[6];
    const float* gk = (const float*)d_in[7];
    const float* bk = (const float*)d_in[8];
    const float* mk = (const float*)d_in[9];
    const float* vk = (const float*)d_in[10];
    const float* Wv = (const float*)d_in[11];
    const float* gv = (const float*)d_in[12];
    const float* bv = (const float*)d_in[13];
    const float* mv = (const float*)d_in[14];
    const float* vv = (const float*)d_in[15];
    float* out = (float*)d_out;

    const size_t MiB = 1048576;
    char* ws = (char*)d_ws;
    unsigned short* Wqh = (unsigned short*)(ws + 0 * 524288);
    unsigned short* Wkh = (unsigned short*)(ws + 1 * 524288);
    unsigned short* Wvh = (unsigned short*)(ws + 2 * 524288);
    unsigned short* vbf = (unsigned short*)(ws + 2 * MiB);    // 16 MiB (C,N)
    unsigned short* qTh = (unsigned short*)(ws + 18 * MiB);   // 16 MiB (N,C)
    unsigned short* kTh = (unsigned short*)(ws + 34 * MiB);   // 16 MiB (N,C)
    unsigned short* xTh = (unsigned short*)(ws + 50 * MiB);   // 16 MiB (N,C)
    unsigned short* pbuf = (unsigned short*)(ws + 66 * MiB);  // 64 MiB fp16 p
    float* mlbuf = (float*)(ws + 130 * MiB);                  // 4 MiB stats
    float* corr  = (float*)(ws + 134 * MiB);                  // 2 MiB corr
    float* linv  = (float*)(ws + 136 * MiB);                  // 64 KiB

    const long BS = (long)N_ * C_;  // elems per batch

    // --- fp16 conversions ---
    split_x_kernel<<<dim3(N_ / 64, C_ / 64, B_), 256, 0, stream>>>(x, xTh);
    split_w_kernel<<<dim3(256), 256, 0, stream>>>(Wq, Wqh);
    split_w_kernel<<<dim3(256), 256, 0, stream>>>(Wk, Wkh);
    split_w_kernel<<<dim3(256), 256, 0, stream>>>(Wv, Wvh);

    // --- projections ---
    gemm_mfma<EPI_PROJT><<<dim3(16, 4, B_), 256, 0, stream>>>(
        Wqh, xTh, 512, 2048, 512, 512, 512, 0, BS, BS, qTh, nullptr,
        nullptr, nullptr, gq, bq, mq, vq);
    gemm_mfma<EPI_PROJT><<<dim3(16, 4, B_), 256, 0, stream>>>(
        Wkh, xTh, 512, 2048, 512, 512, 512, 0, BS, BS, kTh, nullptr,
        nullptr, nullptr, gk, bk, mk, vk);
    gemm_mfma<EPI_PROJV><<<dim3(4, 16, B_), 256, 0, stream>>>(
        xTh, Wvh, 2048, 512, 512, 512, 512, BS, 0, BS, vbf, nullptr,
        nullptr, nullptr, gv, bv, mv, vv);

    // --- logits -> p_local fp16 + per-tile stats (XCD-swizzled grid) ---
    gemm_mfma<EPI_QK><<<dim3(256, 1, B_), 256, 0, stream>>>(
        qTh, kTh, 2048, 2048, 512, 512, 512, BS, BS, (long)N_ * N_, pbuf,
        mlbuf, nullptr, nullptr, nullptr, nullptr, nullptr, nullptr);

    // --- combine stats -> corr, linv ---
    ml_combine_kernel<<<dim3(B_ * N_ / 256), 256, 0, stream>>>(
        mlbuf, corr, linv);

    // --- PV: M=i(2048), N=d(512), K=j(2048); corr-scaled A, /l epilogue ---
    gemm_mfma<EPI_PV><<<dim3(4, 16, B_), 256, 0, stream>>>(
        pbuf, vbf, 2048, 512, 2048, 2048, 2048,
        (long)N_ * N_, BS, BS, out, nullptr, corr, linv,
        nullptr, nullptr, nullptr, nullptr);
}

// Round 8
// 219.840 us; speedup vs baseline: 1.0983x; 1.0983x over previous
//
#include <hip/hip_runtime.h>
#include <cstdint>
#include <cstddef>

#define EPSV 1e-5f
constexpr int B_ = 8;
constexpr int C_ = 512;
constexpr int N_ = 2048;

typedef _Float16 f16x8 __attribute__((ext_vector_type(8)));
typedef float    f32x4 __attribute__((ext_vector_type(4)));

__device__ __forceinline__ unsigned short f16b(float f) {
    _Float16 h = (_Float16)f;
    return __builtin_bit_cast(unsigned short, h);
}

__device__ __forceinline__ void gload_lds16(const void* g, void* l) {
    __builtin_amdgcn_global_load_lds(
        (const __attribute__((address_space(1))) void*)g,
        (__attribute__((address_space(3))) void*)l, 16, 0, 0);
}

// ---------------------------------------------------------------------------
// x (B,C,N) fp32 -> xT (B,N,C) fp16 (transposed so all GEMMs are K-contig)
// ---------------------------------------------------------------------------
__global__ __launch_bounds__(256) void split_x_kernel(
    const float* __restrict__ x, unsigned short* __restrict__ xh)
{
    __shared__ float T[64][65];
    const int b = blockIdx.z, c0 = blockIdx.y * 64, n0 = blockIdx.x * 64;
    const float* xb = x + ((size_t)b * C_ + c0) * N_ + n0;
    const int tid = threadIdx.x;
    const int lr = tid >> 4;
    const int lcn = (tid & 15) * 4;
#pragma unroll
    for (int it = 0; it < 4; ++it) {
        float4 v = *(const float4*)&xb[(size_t)(lr + 16 * it) * N_ + lcn];
        T[lr + 16 * it][lcn + 0] = v.x;
        T[lr + 16 * it][lcn + 1] = v.y;
        T[lr + 16 * it][lcn + 2] = v.z;
        T[lr + 16 * it][lcn + 3] = v.w;
    }
    __syncthreads();
    const int n = tid >> 2, cb = (tid & 3) * 16;
    alignas(16) unsigned short h[16];
#pragma unroll
    for (int i = 0; i < 16; ++i)
        h[i] = f16b(T[cb + i][n]);
    const size_t o = ((size_t)b * N_ + n0 + n) * C_ + c0 + cb;
    *(uint4*)&xh[o]     = *(uint4*)&h[0];
    *(uint4*)&xh[o + 8] = *(uint4*)&h[8];
}

// ---------------------------------------------------------------------------
// W (512x512) fp32 -> fp16
// ---------------------------------------------------------------------------
__global__ __launch_bounds__(256) void split_w_kernel(
    const float* __restrict__ W, unsigned short* __restrict__ wh)
{
    const int i = (blockIdx.x * 256 + threadIdx.x) * 4;
    float4 v = *(const float4*)&W[i];
    alignas(8) unsigned short h[4];
    h[0] = f16b(v.x); h[1] = f16b(v.y); h[2] = f16b(v.z); h[3] = f16b(v.w);
    *(ushort4*)&wh[i] = *(ushort4*)&h[0];
}

// ---------------------------------------------------------------------------
// MFMA GEMM (fp16 in, fp32 acc): C = A * B^T.  m97 structure, 128x128 tile.
// ALL variants use 1-D grids with bz = id & 7: under the HW's round-robin
// XCD assignment (xcd = linear % 8) each XCD serves exactly one batch, so
// per-XCD L2 working sets are batch-local (q/k chunk ~1 MiB; v 2 MiB; xT
// 2 MiB) and panels are fetched from HBM ~once.
// EPI_QK:   s=id>>3 in 4x4 chunks; writes p_local = exp(w - m_tile) fp16
//           (coalesced via LDS repack) + per-64-col-tile stats (m_t,l_t).
// EPI_PV:   A-fragments scaled by corr[b,t,i] (t = k0/64, packed-f16 mul),
//           epilogue * linv[i]; fp32 out at [n*M+m] (d-major)
// EPI_PROJT/PROJV: fused BN, fp16 out at [n*M+m]
// ---------------------------------------------------------------------------
constexpr int EPI_QK = 0, EPI_PV = 1, EPI_PROJT = 2, EPI_PROJV = 3;

template <int EPI>
__global__ __launch_bounds__(256) void gemm_mfma(
    const unsigned short* __restrict__ Ah, const unsigned short* __restrict__ Bh,
    int M, int N, int K, int lda, int ldb,
    long strideA, long strideB, long strideC,
    void* __restrict__ C0, float* __restrict__ ML,
    const float* __restrict__ corr, const float* __restrict__ linv,
    const float* __restrict__ g, const float* __restrict__ bt,
    const float* __restrict__ mu, const float* __restrict__ var)
{
    // QK needs 128x136 fp16 repack tile (34816 B); others 16 KiB.
    __shared__ char smem[(EPI == EPI_QK) ? 34816 : 16384];

    // --- batch-pinned XCD decode (bijective) ---
    const int id = blockIdx.x;
    const int bz = id & 7;
    const int s  = id >> 3;
    int bx, by;
    if constexpr (EPI == EPI_QK) {
        const int chunk = s >> 4, t = s & 15;        // 16 chunks of 4x4 tiles
        bx = (chunk & 3) * 4 + (t & 3);
        by = (chunk >> 2) * 4 + (t >> 2);
    } else if constexpr (EPI == EPI_PV || EPI == EPI_PROJV) {
        bx = s & 3;  by = s >> 2;                    // N=512: 4 x-blocks
    } else {                                         // PROJT: N=2048, M=512
        bx = s & 15; by = s >> 4;
    }
    const int n0 = bx * 128;
    const int m0 = by * 128;

    const unsigned short* Ahb = Ah + (size_t)bz * strideA;
    const unsigned short* Bhb = Bh + (size_t)bz * strideB;

    const int tid = threadIdx.x;
    const int lane = tid & 63;
    const int wv = tid >> 6;
    const int wr = wv >> 1, wc = wv & 1;
    const int l4 = lane >> 4, l15 = lane & 15;
    const int srow = lane >> 2, scol8 = (lane & 3) * 8;

    f32x4 acc[4][4] = {};
    float ca[4];                       // EPI_PV: per-fm corr for current tile

    for (int k0 = 0; k0 < K; k0 += 32) {
        if constexpr (EPI == EPI_PV) {
            if ((k0 & 63) == 0) {
                const int t = k0 >> 6;
                const float* cb = corr + ((size_t)bz * 32 + t) * 2048 + m0;
#pragma unroll
                for (int f = 0; f < 4; ++f)
                    ca[f] = cb[wr * 64 + f * 16 + l15];
            }
        }
#pragma unroll
        for (int cc = 0; cc < 2; ++cc) {
            const int c = wv * 2 + cc;
            const size_t aoff = (size_t)(m0 + c * 16 + srow) * lda + k0 + scol8;
            const size_t boff = (size_t)(n0 + c * 16 + srow) * ldb + k0 + scol8;
            gload_lds16(Ahb + aoff, smem + c * 1024);
            gload_lds16(Bhb + boff, smem + 8192 + c * 1024);
        }
        __syncthreads();

        f16x8 ah[4], bh[4];
#pragma unroll
        for (int f = 0; f < 4; ++f) {
            const int arow = wr * 64 + f * 16 + l15;
            const int brow = wc * 64 + f * 16 + l15;
            ah[f] = *(const f16x8*)(smem + arow * 64 + l4 * 16);
            bh[f] = *(const f16x8*)(smem + 8192 + brow * 64 + l4 * 16);
        }
        if constexpr (EPI == EPI_PV) {
#pragma unroll
            for (int f = 0; f < 4; ++f) {
                const _Float16 cf = (_Float16)ca[f];
                ah[f] = ah[f] * cf;        // packed v_pk_mul_f16
            }
        }
#pragma unroll
        for (int fm = 0; fm < 4; ++fm)
#pragma unroll
            for (int fn = 0; fn < 4; ++fn)
                acc[fm][fn] = __builtin_amdgcn_mfma_f32_16x16x32_f16(
                    ah[fm], bh[fn], acc[fm][fn], 0, 0, 0);
        __syncthreads();
    }

    if constexpr (EPI == EPI_QK) {
        // stats + exp into LDS repack tile, then coalesced 16B stores.
        unsigned short* H = (unsigned short*)C0 + (size_t)bz * strideC;
        unsigned short* pl = (unsigned short*)smem;      // [128][136] fp16
        const size_t mbase =
            (((size_t)bz * 32 + bx * 2 + wc) * 2) * 2048;
#pragma unroll
        for (int fm = 0; fm < 4; ++fm) {
#pragma unroll
            for (int r = 0; r < 4; ++r) {
                float mx = fmaxf(fmaxf(acc[fm][0][r], acc[fm][1][r]),
                                 fmaxf(acc[fm][2][r], acc[fm][3][r]));
#pragma unroll
                for (int off = 1; off < 16; off <<= 1)
                    mx = fmaxf(mx, __shfl_xor(mx, off));
                float pe[4];
                float s2 = 0.f;
#pragma unroll
                for (int fn = 0; fn < 4; ++fn) {
                    pe[fn] = __expf(acc[fm][fn][r] - mx);
                    s2 += pe[fn];
                }
#pragma unroll
                for (int off = 1; off < 16; off <<= 1)
                    s2 += __shfl_xor(s2, off);
                const int rloc = wr * 64 + fm * 16 + l4 * 4 + r;
                if (l15 == 0) {
                    ML[mbase + m0 + rloc] = mx;
                    ML[mbase + 2048 + m0 + rloc] = s2;
                }
#pragma unroll
                for (int fn = 0; fn < 4; ++fn)
                    pl[rloc * 136 + wc * 64 + fn * 16 + l15] = f16b(pe[fn]);
            }
        }
        __syncthreads();
#pragma unroll
        for (int it = 0; it < 8; ++it) {
            const int rr = (tid >> 4) + it * 16;
            const int cc8 = (tid & 15) * 8;
            *(uint4*)&H[(size_t)(m0 + rr) * N + n0 + cc8] =
                *(const uint4*)&pl[rr * 136 + cc8];
        }
    } else if constexpr (EPI == EPI_PV) {
        float* Cb = (float*)C0 + (size_t)bz * strideC;
        const float* lb = linv + (size_t)bz * 2048;
        float lv[4][4];
#pragma unroll
        for (int fm = 0; fm < 4; ++fm)
#pragma unroll
            for (int r = 0; r < 4; ++r)
                lv[fm][r] = lb[m0 + wr * 64 + fm * 16 + l4 * 4 + r];
#pragma unroll
        for (int fm = 0; fm < 4; ++fm)
#pragma unroll
            for (int fn = 0; fn < 4; ++fn) {
                const int m = m0 + wr * 64 + fm * 16 + l4 * 4;
                const int n = n0 + wc * 64 + fn * 16 + l15;
                float4 o4 = make_float4(acc[fm][fn][0] * lv[fm][0],
                                        acc[fm][fn][1] * lv[fm][1],
                                        acc[fm][fn][2] * lv[fm][2],
                                        acc[fm][fn][3] * lv[fm][3]);
                *(float4*)&Cb[(size_t)n * M + m] = o4;
            }
    } else {
#pragma unroll
        for (int fm = 0; fm < 4; ++fm) {
#pragma unroll
            for (int fn = 0; fn < 4; ++fn) {
                const int m = m0 + wr * 64 + fm * 16 + l4 * 4;
                const int n = n0 + wc * 64 + fn * 16 + l15;
                unsigned short* H = (unsigned short*)C0 + (size_t)bz * strideC;
                alignas(8) unsigned short h4[4];
                if constexpr (EPI == EPI_PROJT) {
#pragma unroll
                    for (int r = 0; r < 4; ++r) {
                        const int o = m + r;
                        const float sc = g[o] * rsqrtf(var[o] + EPSV);
                        const float sh = bt[o] - mu[o] * sc;
                        h4[r] = f16b(acc[fm][fn][r] * sc + sh);
                    }
                } else {  // EPI_PROJV
                    const float sc = g[n] * rsqrtf(var[n] + EPSV);
                    const float sh = bt[n] - mu[n] * sc;
#pragma unroll
                    for (int r = 0; r < 4; ++r)
                        h4[r] = f16b(acc[fm][fn][r] * sc + sh);
                }
                *(ushort4*)&H[(size_t)n * M + m] = *(ushort4*)&h4[0];
            }
        }
    }
}

// ---------------------------------------------------------------------------
// Combine 32 per-tile (m,l) partials: m_global, linv = 1/l_global, and
// corr[b,t,i] = exp(m_t - m_global).  One thread per (b, i).
// ---------------------------------------------------------------------------
__global__ __launch_bounds__(256) void ml_combine_kernel(
    const float* __restrict__ ml, float* __restrict__ corr,
    float* __restrict__ linv)
{
    const int idx = blockIdx.x * 256 + threadIdx.x;   // b*2048 + i
    const int b = idx >> 11, i = idx & 2047;
    const float* base = ml + ((size_t)b * 32) * 2 * 2048 + i;
    float M = -3.0e38f;
#pragma unroll 8
    for (int t = 0; t < 32; ++t)
        M = fmaxf(M, base[(size_t)t * 4096]);
    float L = 0.f;
    float* cb = corr + (size_t)b * 32 * 2048 + i;
#pragma unroll 8
    for (int t = 0; t < 32; ++t) {
        const float c = __expf(base[(size_t)t * 4096] - M);
        L += c * base[(size_t)t * 4096 + 2048];
        cb[(size_t)t * 2048] = c;
    }
    linv[idx] = 1.0f / L;
}

// ---------------------------------------------------------------------------
extern "C" void kernel_launch(void* const* d_in, const int* in_sizes, int n_in,
                              void* d_out, int out_size, void* d_ws, size_t ws_size,
                              hipStream_t stream)
{
    (void)in_sizes; (void)n_in; (void)out_size; (void)ws_size;
    const float* x  = (const float*)d_in[0];
    const float* Wq = (const float*)d_in[1];
    const float* gq = (const float*)d_in[2];
    const float* bq = (const float*)d_in[3];
    const float* mq = (const float*)d_in[4];
    const float* vq = (const float*)d_in[5];
    const float* Wk = (const float*)d_in[6];
    const float* gk = (const float*)d_in[7];
    const float* bk = (const float*)d_in[8];
    const float* mk = (const float*)d_in[9];
    const float* vk = (const float*)d_in[10];
    const float* Wv = (const float*)d_in[11];
    const float* gv = (const float*)d_in[12];
    const float* bv = (const float*)d_in[13];
    const float* mv = (const float*)d_in[14];
    const float* vv = (const float*)d_in[15];
    float* out = (float*)d_out;

    const size_t MiB = 1048576;
    char* ws = (char*)d_ws;
    unsigned short* Wqh = (unsigned short*)(ws + 0 * 524288);
    unsigned short* Wkh = (unsigned short*)(ws + 1 * 524288);
    unsigned short* Wvh = (unsigned short*)(ws + 2 * 524288);
    unsigned short* vbf = (unsigned short*)(ws + 2 * MiB);    // 16 MiB (C,N)
    unsigned short* qTh = (unsigned short*)(ws + 18 * MiB);   // 16 MiB (N,C)
    unsigned short* kTh = (unsigned short*)(ws + 34 * MiB);   // 16 MiB (N,C)
    unsigned short* xTh = (unsigned short*)(ws + 50 * MiB);   // 16 MiB (N,C)
    unsigned short* pbuf = (unsigned short*)(ws + 66 * MiB);  // 64 MiB fp16 p
    float* mlbuf = (float*)(ws + 130 * MiB);                  // 4 MiB stats
    float* corr  = (float*)(ws + 134 * MiB);                  // 2 MiB corr
    float* linv  = (float*)(ws + 136 * MiB);                  // 64 KiB

    const long BS = (long)N_ * C_;  // elems per batch

    // --- fp16 conversions ---
    split_x_kernel<<<dim3(N_ / 64, C_ / 64, B_), 256, 0, stream>>>(x, xTh);
    split_w_kernel<<<dim3(256), 256, 0, stream>>>(Wq, Wqh);
    split_w_kernel<<<dim3(256), 256, 0, stream>>>(Wk, Wkh);
    split_w_kernel<<<dim3(256), 256, 0, stream>>>(Wv, Wvh);

    // --- projections (1-D grid, batch-pinned XCD) ---
    gemm_mfma<EPI_PROJT><<<dim3(512), 256, 0, stream>>>(
        Wqh, xTh, 512, 2048, 512, 512, 512, 0, BS, BS, qTh, nullptr,
        nullptr, nullptr, gq, bq, mq, vq);
    gemm_mfma<EPI_PROJT><<<dim3(512), 256, 0, stream>>>(
        Wkh, xTh, 512, 2048, 512, 512, 512, 0, BS, BS, kTh, nullptr,
        nullptr, nullptr, gk, bk, mk, vk);
    gemm_mfma<EPI_PROJV><<<dim3(512), 256, 0, stream>>>(
        xTh, Wvh, 2048, 512, 512, 512, 512, BS, 0, BS, vbf, nullptr,
        nullptr, nullptr, gv, bv, mv, vv);

    // --- logits -> p_local fp16 + per-tile stats ---
    gemm_mfma<EPI_QK><<<dim3(2048), 256, 0, stream>>>(
        qTh, kTh, 2048, 2048, 512, 512, 512, BS, BS, (long)N_ * N_, pbuf,
        mlbuf, nullptr, nullptr, nullptr, nullptr, nullptr, nullptr);

    // --- combine stats -> corr, linv ---
    ml_combine_kernel<<<dim3(B_ * N_ / 256), 256, 0, stream>>>(
        mlbuf, corr, linv);

    // --- PV: M=i(2048), N=d(512), K=j(2048); corr-scaled A, /l epilogue ---
    gemm_mfma<EPI_PV><<<dim3(512), 256, 0, stream>>>(
        pbuf, vbf, 2048, 512, 2048, 2048, 2048,
        (long)N_ * N_, BS, BS, out, nullptr, corr, linv,
        nullptr, nullptr, nullptr, nullptr);
}

// Round 9
// 205.611 us; speedup vs baseline: 1.1743x; 1.0692x over previous
//
#include <hip/hip_runtime.h>
#include <cstdint>
#include <cstddef>

#define EPSV 1e-5f
constexpr int B_ = 8;
constexpr int C_ = 512;
constexpr int N_ = 2048;

typedef _Float16 f16x8 __attribute__((ext_vector_type(8)));
typedef float    f32x4 __attribute__((ext_vector_type(4)));

__device__ __forceinline__ unsigned short f16b(float f) {
    _Float16 h = (_Float16)f;
    return __builtin_bit_cast(unsigned short, h);
}

__device__ __forceinline__ void gload_lds16(const void* g, void* l) {
    __builtin_amdgcn_global_load_lds(
        (const __attribute__((address_space(1))) void*)g,
        (__attribute__((address_space(3))) void*)l, 16, 0, 0);
}

// ---------------------------------------------------------------------------
// x (B,C,N) fp32 -> xT (B,N,C) fp16
// ---------------------------------------------------------------------------
__global__ __launch_bounds__(256) void split_x_kernel(
    const float* __restrict__ x, unsigned short* __restrict__ xh)
{
    __shared__ float T[64][65];
    const int b = blockIdx.z, c0 = blockIdx.y * 64, n0 = blockIdx.x * 64;
    const float* xb = x + ((size_t)b * C_ + c0) * N_ + n0;
    const int tid = threadIdx.x;
    const int lr = tid >> 4;
    const int lcn = (tid & 15) * 4;
#pragma unroll
    for (int it = 0; it < 4; ++it) {
        float4 v = *(const float4*)&xb[(size_t)(lr + 16 * it) * N_ + lcn];
        T[lr + 16 * it][lcn + 0] = v.x;
        T[lr + 16 * it][lcn + 1] = v.y;
        T[lr + 16 * it][lcn + 2] = v.z;
        T[lr + 16 * it][lcn + 3] = v.w;
    }
    __syncthreads();
    const int n = tid >> 2, cb = (tid & 3) * 16;
    alignas(16) unsigned short h[16];
#pragma unroll
    for (int i = 0; i < 16; ++i)
        h[i] = f16b(T[cb + i][n]);
    const size_t o = ((size_t)b * N_ + n0 + n) * C_ + c0 + cb;
    *(uint4*)&xh[o]     = *(uint4*)&h[0];
    *(uint4*)&xh[o + 8] = *(uint4*)&h[8];
}

__global__ __launch_bounds__(256) void split_w_kernel(
    const float* __restrict__ W, unsigned short* __restrict__ wh)
{
    const int i = (blockIdx.x * 256 + threadIdx.x) * 4;
    float4 v = *(const float4*)&W[i];
    alignas(8) unsigned short h[4];
    h[0] = f16b(v.x); h[1] = f16b(v.y); h[2] = f16b(v.z); h[3] = f16b(v.w);
    *(ushort4*)&wh[i] = *(ushort4*)&h[0];
}

// ---------------------------------------------------------------------------
// Projection GEMMs (m97 structure, 128x128): unchanged from round 8.
// ---------------------------------------------------------------------------
constexpr int EPI_QK = 0, EPI_PV = 1, EPI_PROJT = 2, EPI_PROJV = 3;

template <int EPI>
__global__ __launch_bounds__(256) void gemm_mfma(
    const unsigned short* __restrict__ Ah, const unsigned short* __restrict__ Bh,
    int M, int N, int K, int lda, int ldb,
    long strideA, long strideB, long strideC,
    void* __restrict__ C0,
    const float* __restrict__ g, const float* __restrict__ bt,
    const float* __restrict__ mu, const float* __restrict__ var)
{
    __shared__ char smem[16384];

    const int id = blockIdx.x;
    const int bz = id & 7;
    const int s  = id >> 3;
    int bx, by;
    if constexpr (EPI == EPI_PROJV) { bx = s & 3;  by = s >> 2; }
    else                            { bx = s & 15; by = s >> 4; }
    const int n0 = bx * 128;
    const int m0 = by * 128;

    const unsigned short* Ahb = Ah + (size_t)bz * strideA;
    const unsigned short* Bhb = Bh + (size_t)bz * strideB;

    const int tid = threadIdx.x;
    const int lane = tid & 63;
    const int wv = tid >> 6;
    const int wr = wv >> 1, wc = wv & 1;
    const int l4 = lane >> 4, l15 = lane & 15;
    const int srow = lane >> 2, scol8 = (lane & 3) * 8;

    f32x4 acc[4][4] = {};

    for (int k0 = 0; k0 < K; k0 += 32) {
#pragma unroll
        for (int cc = 0; cc < 2; ++cc) {
            const int c = wv * 2 + cc;
            const size_t aoff = (size_t)(m0 + c * 16 + srow) * lda + k0 + scol8;
            const size_t boff = (size_t)(n0 + c * 16 + srow) * ldb + k0 + scol8;
            gload_lds16(Ahb + aoff, smem + c * 1024);
            gload_lds16(Bhb + boff, smem + 8192 + c * 1024);
        }
        __syncthreads();

        f16x8 ah[4], bh[4];
#pragma unroll
        for (int f = 0; f < 4; ++f) {
            const int arow = wr * 64 + f * 16 + l15;
            const int brow = wc * 64 + f * 16 + l15;
            ah[f] = *(const f16x8*)(smem + arow * 64 + l4 * 16);
            bh[f] = *(const f16x8*)(smem + 8192 + brow * 64 + l4 * 16);
        }
#pragma unroll
        for (int fm = 0; fm < 4; ++fm)
#pragma unroll
            for (int fn = 0; fn < 4; ++fn)
                acc[fm][fn] = __builtin_amdgcn_mfma_f32_16x16x32_f16(
                    ah[fm], bh[fn], acc[fm][fn], 0, 0, 0);
        __syncthreads();
    }

#pragma unroll
    for (int fm = 0; fm < 4; ++fm) {
#pragma unroll
        for (int fn = 0; fn < 4; ++fn) {
            const int m = m0 + wr * 64 + fm * 16 + l4 * 4;
            const int n = n0 + wc * 64 + fn * 16 + l15;
            unsigned short* H = (unsigned short*)C0 + (size_t)bz * strideC;
            alignas(8) unsigned short h4[4];
            if constexpr (EPI == EPI_PROJT) {
#pragma unroll
                for (int r = 0; r < 4; ++r) {
                    const int o = m + r;
                    const float sc = g[o] * rsqrtf(var[o] + EPSV);
                    const float sh = bt[o] - mu[o] * sc;
                    h4[r] = f16b(acc[fm][fn][r] * sc + sh);
                }
            } else {  // EPI_PROJV
                const float sc = g[n] * rsqrtf(var[n] + EPSV);
                const float sh = bt[n] - mu[n] * sc;
#pragma unroll
                for (int r = 0; r < 4; ++r)
                    h4[r] = f16b(acc[fm][fn][r] * sc + sh);
            }
            *(ushort4*)&H[(size_t)n * M + m] = *(ushort4*)&h4[0];
        }
    }
}

// ---------------------------------------------------------------------------
// attn256<EPI>: 256x128 tile, BK=64, 8 waves, 512 threads, tri-buffered LDS
// (3 x 48KB), counted vmcnt(6), T2 XOR-swizzle (slot ^= row&7 on both staging
// source and ds_read — same involution), setprio around MFMA.
// QK (waves 4Mx2N, per-wave 64x64): epilogue = exp/stats/LDS-repack (reuses
//   staging LDS after the loop).  Accumulation order identical to round 8.
// PV (waves 2Mx4N, per-wave 128x32): corr preloaded to LDS as fp16 (keeps
//   per-tile corr reads out of vmcnt); epilogue * linv.
// ---------------------------------------------------------------------------
template <int EPI>
__global__ __launch_bounds__(512, 2) void attn256(
    const unsigned short* __restrict__ Ah, const unsigned short* __restrict__ Bh,
    int K, int lda, int ldb, long strideA, long strideB, long strideC,
    void* __restrict__ C0, float* __restrict__ ML,
    const float* __restrict__ corr, const float* __restrict__ linv)
{
    constexpr int BUFSZ = 49152;                  // 32KB A + 16KB B
    __shared__ char smem[(EPI == EPI_PV) ? 163840 : 147456];

    const int id = blockIdx.x;
    const int bz = id & 7;                        // batch-pinned XCD
    const int s  = id >> 3;
    int bx, by;
    if constexpr (EPI == EPI_QK) { bx = s & 15; by = s >> 4; }   // 16 j x 8 i
    else                         { bx = s & 3;  by = s >> 2; }   // 4 d x 8 i
    const int n0 = bx * 128;
    const int m0 = by * 256;

    const unsigned short* Ahb = Ah + (size_t)bz * strideA;
    const unsigned short* Bhb = Bh + (size_t)bz * strideB;

    const int tid  = threadIdx.x;
    const int lane = tid & 63;
    const int wv   = tid >> 6;
    const int wr   = (EPI == EPI_QK) ? (wv >> 1) : (wv >> 2);
    const int wc   = (EPI == EPI_QK) ? (wv & 1)  : (wv & 3);
    const int WRB  = (EPI == EPI_QK) ? wr * 64 : wr * 128;
    const int WCB  = (EPI == EPI_QK) ? wc * 64 : wc * 32;
    constexpr int MF = (EPI == EPI_QK) ? 4 : 8;
    constexpr int NF = (EPI == EPI_QK) ? 4 : 2;
    const int l4 = lane >> 4, l15 = lane & 15;

    // staging decode (shared by all 6 units)
    const int srow = tid >> 3;                    // 0..63 row within unit
    const int sslot = ((tid & 7) ^ (srow & 7)) * 8;   // pre-swizzled source col

    unsigned short* corrLds = (unsigned short*)(smem + 147456);  // PV only
    if constexpr (EPI == EPI_PV) {
        for (int idx = tid; idx < 2048; idx += 512) {
            const int t = idx >> 6, i4 = (idx & 63) * 4;
            float4 c4 = *(const float4*)&corr[((size_t)bz * 32 + t) * 2048 + m0 + i4];
            alignas(8) unsigned short h4[4] =
                {f16b(c4.x), f16b(c4.y), f16b(c4.z), f16b(c4.w)};
            *(ushort4*)&corrLds[(size_t)t * 256 + i4] = *(ushort4*)&h4[0];
        }
        __syncthreads();
    }

#define STAGE(t)                                                              \
    {                                                                         \
        char* dst = smem + ((t) % 3) * BUFSZ;                                 \
        const unsigned short* asrc =                                          \
            Ahb + (size_t)(m0 + srow) * lda + (t) * 64 + sslot;               \
        _Pragma("unroll")                                                     \
        for (int u = 0; u < 4; ++u)                                           \
            gload_lds16(asrc + (size_t)(u * 64) * lda,                        \
                        dst + u * 8192 + tid * 16);                           \
        const unsigned short* bsrc =                                          \
            Bhb + (size_t)(n0 + srow) * ldb + (t) * 64 + sslot;               \
        _Pragma("unroll")                                                     \
        for (int u = 0; u < 2; ++u)                                           \
            gload_lds16(bsrc + (size_t)(u * 64) * ldb,                        \
                        dst + 32768 + u * 8192 + tid * 16);                   \
    }

    f32x4 acc[MF][NF] = {};
    const int NT = K / 64;

    STAGE(0);
    STAGE(1);

    for (int t = 0; t < NT; ++t) {
        char* cur = smem + (t % 3) * BUFSZ;
        if (t + 2 < NT) {
            asm volatile("s_waitcnt vmcnt(6)" ::: "memory");
        } else {
            asm volatile("s_waitcnt vmcnt(0)" ::: "memory");
        }
        __builtin_amdgcn_s_barrier();
        asm volatile("" ::: "memory");
        if (t + 2 < NT) STAGE(t + 2);

        f16x8 ah[MF][2], bh[NF][2];
#pragma unroll
        for (int m = 0; m < MF; ++m) {
            const int row = WRB + m * 16 + l15;
#pragma unroll
            for (int kk = 0; kk < 2; ++kk)
                ah[m][kk] = *(const f16x8*)(cur + row * 128 +
                                            (((kk << 2) | l4) ^ (row & 7)) * 16);
        }
#pragma unroll
        for (int n = 0; n < NF; ++n) {
            const int row = WCB + n * 16 + l15;
#pragma unroll
            for (int kk = 0; kk < 2; ++kk)
                bh[n][kk] = *(const f16x8*)(cur + 32768 + row * 128 +
                                            (((kk << 2) | l4) ^ (row & 7)) * 16);
        }
        if constexpr (EPI == EPI_PV) {
#pragma unroll
            for (int m = 0; m < MF; ++m) {
                const _Float16 cf = ((const _Float16*)corrLds)
                    [(size_t)t * 256 + WRB + m * 16 + l15];
                ah[m][0] = ah[m][0] * cf;
                ah[m][1] = ah[m][1] * cf;
            }
        }
        __builtin_amdgcn_s_setprio(1);
#pragma unroll
        for (int kk = 0; kk < 2; ++kk)
#pragma unroll
            for (int m = 0; m < MF; ++m)
#pragma unroll
                for (int n = 0; n < NF; ++n)
                    acc[m][n] = __builtin_amdgcn_mfma_f32_16x16x32_f16(
                        ah[m][kk], bh[n][kk], acc[m][n], 0, 0, 0);
        __builtin_amdgcn_s_setprio(0);
    }
#undef STAGE

    if constexpr (EPI == EPI_QK) {
        __syncthreads();                           // loop fully drained
        unsigned short* H = (unsigned short*)C0 + (size_t)bz * strideC;
        unsigned short* pl = (unsigned short*)smem;          // [256][136]
        const size_t mbase = (((size_t)bz * 32 + bx * 2 + wc) * 2) * 2048;
#pragma unroll
        for (int fm = 0; fm < 4; ++fm) {
#pragma unroll
            for (int r = 0; r < 4; ++r) {
                float mx = fmaxf(fmaxf(acc[fm][0][r], acc[fm][1][r]),
                                 fmaxf(acc[fm][2][r], acc[fm][3][r]));
#pragma unroll
                for (int off = 1; off < 16; off <<= 1)
                    mx = fmaxf(mx, __shfl_xor(mx, off));
                float pe[4];
                float s2 = 0.f;
#pragma unroll
                for (int fn = 0; fn < 4; ++fn) {
                    pe[fn] = __expf(acc[fm][fn][r] - mx);
                    s2 += pe[fn];
                }
#pragma unroll
                for (int off = 1; off < 16; off <<= 1)
                    s2 += __shfl_xor(s2, off);
                const int rloc = WRB + fm * 16 + l4 * 4 + r;   // 0..255
                if (l15 == 0) {
                    ML[mbase + m0 + rloc] = mx;
                    ML[mbase + 2048 + m0 + rloc] = s2;
                }
#pragma unroll
                for (int fn = 0; fn < 4; ++fn)
                    pl[rloc * 136 + WCB + fn * 16 + l15] = f16b(pe[fn]);
            }
        }
        __syncthreads();
#pragma unroll
        for (int it = 0; it < 8; ++it) {
            const int rr = (tid >> 4) + it * 32;
            const int cc8 = (tid & 15) * 8;
            *(uint4*)&H[(size_t)(m0 + rr) * 2048 + n0 + cc8] =
                *(const uint4*)&pl[rr * 136 + cc8];
        }
    } else {  // EPI_PV
        float* Cb = (float*)C0 + (size_t)bz * strideC;
        const float* lb = linv + (size_t)bz * 2048;
#pragma unroll
        for (int m = 0; m < MF; ++m) {
            const int mrow = m0 + WRB + m * 16 + l4 * 4;
            float lv[4];
#pragma unroll
            for (int r = 0; r < 4; ++r)
                lv[r] = lb[mrow + r];
#pragma unroll
            for (int n = 0; n < NF; ++n) {
                const int col = n0 + WCB + n * 16 + l15;
                float4 o4 = make_float4(acc[m][n][0] * lv[0],
                                        acc[m][n][1] * lv[1],
                                        acc[m][n][2] * lv[2],
                                        acc[m][n][3] * lv[3]);
                *(float4*)&Cb[(size_t)col * 2048 + mrow] = o4;
            }
        }
    }
}

// ---------------------------------------------------------------------------
// Combine 32 per-tile (m,l) partials -> corr, linv.
// ---------------------------------------------------------------------------
__global__ __launch_bounds__(256) void ml_combine_kernel(
    const float* __restrict__ ml, float* __restrict__ corr,
    float* __restrict__ linv)
{
    const int idx = blockIdx.x * 256 + threadIdx.x;   // b*2048 + i
    const int b = idx >> 11, i = idx & 2047;
    const float* base = ml + ((size_t)b * 32) * 2 * 2048 + i;
    float M = -3.0e38f;
#pragma unroll 8
    for (int t = 0; t < 32; ++t)
        M = fmaxf(M, base[(size_t)t * 4096]);
    float L = 0.f;
    float* cb = corr + (size_t)b * 32 * 2048 + i;
#pragma unroll 8
    for (int t = 0; t < 32; ++t) {
        const float c = __expf(base[(size_t)t * 4096] - M);
        L += c * base[(size_t)t * 4096 + 2048];
        cb[(size_t)t * 2048] = c;
    }
    linv[idx] = 1.0f / L;
}

// ---------------------------------------------------------------------------
extern "C" void kernel_launch(void* const* d_in, const int* in_sizes, int n_in,
                              void* d_out, int out_size, void* d_ws, size_t ws_size,
                              hipStream_t stream)
{
    (void)in_sizes; (void)n_in; (void)out_size; (void)ws_size;
    const float* x  = (const float*)d_in[0];
    const float* Wq = (const float*)d_in[1];
    const float* gq = (const float*)d_in[2];
    const float* bq = (const float*)d_in[3];
    const float* mq = (const float*)d_in[4];
    const float* vq = (const float*)d_in[5];
    const float* Wk = (const float*)d_in[6];
    const float* gk = (const float*)d_in[7];
    const float* bk = (const float*)d_in[8];
    const float* mk = (const float*)d_in[9];
    const float* vk = (const float*)d_in[10];
    const float* Wv = (const float*)d_in[11];
    const float* gv = (const float*)d_in[12];
    const float* bv = (const float*)d_in[13];
    const float* mv = (const float*)d_in[14];
    const float* vv = (const float*)d_in[15];
    float* out = (float*)d_out;

    const size_t MiB = 1048576;
    char* ws = (char*)d_ws;
    unsigned short* Wqh = (unsigned short*)(ws + 0 * 524288);
    unsigned short* Wkh = (unsigned short*)(ws + 1 * 524288);
    unsigned short* Wvh = (unsigned short*)(ws + 2 * 524288);
    unsigned short* vbf = (unsigned short*)(ws + 2 * MiB);    // 16 MiB (C,N)
    unsigned short* qTh = (unsigned short*)(ws + 18 * MiB);   // 16 MiB (N,C)
    unsigned short* kTh = (unsigned short*)(ws + 34 * MiB);   // 16 MiB (N,C)
    unsigned short* xTh = (unsigned short*)(ws + 50 * MiB);   // 16 MiB (N,C)
    unsigned short* pbuf = (unsigned short*)(ws + 66 * MiB);  // 64 MiB fp16 p
    float* mlbuf = (float*)(ws + 130 * MiB);                  // 4 MiB stats
    float* corr  = (float*)(ws + 134 * MiB);                  // 2 MiB corr
    float* linv  = (float*)(ws + 136 * MiB);                  // 64 KiB

    const long BS = (long)N_ * C_;

    // --- fp16 conversions ---
    split_x_kernel<<<dim3(N_ / 64, C_ / 64, B_), 256, 0, stream>>>(x, xTh);
    split_w_kernel<<<dim3(256), 256, 0, stream>>>(Wq, Wqh);
    split_w_kernel<<<dim3(256), 256, 0, stream>>>(Wk, Wkh);
    split_w_kernel<<<dim3(256), 256, 0, stream>>>(Wv, Wvh);

    // --- projections (m97, batch-pinned) ---
    gemm_mfma<EPI_PROJT><<<dim3(512), 256, 0, stream>>>(
        Wqh, xTh, 512, 2048, 512, 512, 512, 0, BS, BS, qTh, gq, bq, mq, vq);
    gemm_mfma<EPI_PROJT><<<dim3(512), 256, 0, stream>>>(
        Wkh, xTh, 512, 2048, 512, 512, 512, 0, BS, BS, kTh, gk, bk, mk, vk);
    gemm_mfma<EPI_PROJV><<<dim3(512), 256, 0, stream>>>(
        xTh, Wvh, 2048, 512, 512, 512, 512, BS, 0, BS, vbf, gv, bv, mv, vv);

    // --- logits -> p_local fp16 + per-tile stats (256x128, counted vmcnt) ---
    attn256<EPI_QK><<<dim3(1024), 512, 0, stream>>>(
        qTh, kTh, 512, 512, 512, BS, BS, (long)N_ * N_, pbuf,
        mlbuf, nullptr, nullptr);

    // --- combine stats -> corr, linv ---
    ml_combine_kernel<<<dim3(B_ * N_ / 256), 256, 0, stream>>>(
        mlbuf, corr, linv);

    // --- PV (256x128, counted vmcnt, corr-scaled, /l epilogue) ---
    attn256<EPI_PV><<<dim3(256), 512, 0, stream>>>(
        pbuf, vbf, 2048, 2048, 2048, (long)N_ * N_, BS, BS, out,
        nullptr, corr, linv);
}

// Round 10
// 179.706 us; speedup vs baseline: 1.3436x; 1.1442x over previous
//
#include <hip/hip_runtime.h>
#include <cstdint>
#include <cstddef>

#define EPSV 1e-5f
constexpr int B_ = 8;
constexpr int C_ = 512;
constexpr int N_ = 2048;

typedef _Float16 f16x8 __attribute__((ext_vector_type(8)));
typedef float    f32x4 __attribute__((ext_vector_type(4)));

__device__ __forceinline__ unsigned short f16b(float f) {
    _Float16 h = (_Float16)f;
    return __builtin_bit_cast(unsigned short, h);
}

__device__ __forceinline__ void gload_lds16(const void* g, void* l) {
    __builtin_amdgcn_global_load_lds(
        (const __attribute__((address_space(1))) void*)g,
        (__attribute__((address_space(3))) void*)l, 16, 0, 0);
}

// ---------------------------------------------------------------------------
// x (B,C,N) fp32 -> xT (B,N,C) fp16
// ---------------------------------------------------------------------------
__global__ __launch_bounds__(256) void split_x_kernel(
    const float* __restrict__ x, unsigned short* __restrict__ xh)
{
    __shared__ float T[64][65];
    const int b = blockIdx.z, c0 = blockIdx.y * 64, n0 = blockIdx.x * 64;
    const float* xb = x + ((size_t)b * C_ + c0) * N_ + n0;
    const int tid = threadIdx.x;
    const int lr = tid >> 4;
    const int lcn = (tid & 15) * 4;
#pragma unroll
    for (int it = 0; it < 4; ++it) {
        float4 v = *(const float4*)&xb[(size_t)(lr + 16 * it) * N_ + lcn];
        T[lr + 16 * it][lcn + 0] = v.x;
        T[lr + 16 * it][lcn + 1] = v.y;
        T[lr + 16 * it][lcn + 2] = v.z;
        T[lr + 16 * it][lcn + 3] = v.w;
    }
    __syncthreads();
    const int n = tid >> 2, cb = (tid & 3) * 16;
    alignas(16) unsigned short h[16];
#pragma unroll
    for (int i = 0; i < 16; ++i)
        h[i] = f16b(T[cb + i][n]);
    const size_t o = ((size_t)b * N_ + n0 + n) * C_ + c0 + cb;
    *(uint4*)&xh[o]     = *(uint4*)&h[0];
    *(uint4*)&xh[o + 8] = *(uint4*)&h[8];
}

__global__ __launch_bounds__(256) void split_w_kernel(
    const float* __restrict__ W, unsigned short* __restrict__ wh)
{
    const int i = (blockIdx.x * 256 + threadIdx.x) * 4;
    float4 v = *(const float4*)&W[i];
    alignas(8) unsigned short h[4];
    h[0] = f16b(v.x); h[1] = f16b(v.y); h[2] = f16b(v.z); h[3] = f16b(v.w);
    *(ushort4*)&wh[i] = *(ushort4*)&h[0];
}

// concat BN params of q and k into stacked [1024] arrays
__global__ __launch_bounds__(512) void param_concat_kernel(
    const float* gq, const float* bq, const float* mq, const float* vq,
    const float* gk, const float* bk, const float* mk, const float* vk,
    float* sg, float* sb, float* sm, float* sv)
{
    const int i = threadIdx.x;           // 0..511
    sg[i] = gq[i];       sg[512 + i] = gk[i];
    sb[i] = bq[i];       sb[512 + i] = bk[i];
    sm[i] = mq[i];       sm[512 + i] = mk[i];
    sv[i] = vq[i];       sv[512 + i] = vk[i];
}

// ---------------------------------------------------------------------------
// 128x128 m97 GEMM — kept for PROJV only (N=512 can't fill the GPU at 256²).
// ---------------------------------------------------------------------------
__global__ __launch_bounds__(256) void projv_mfma(
    const unsigned short* __restrict__ Ah, const unsigned short* __restrict__ Bh,
    int M, int N, int K, int lda, int ldb,
    long strideA, long strideB, long strideC,
    void* __restrict__ C0,
    const float* __restrict__ g, const float* __restrict__ bt,
    const float* __restrict__ mu, const float* __restrict__ var)
{
    __shared__ char smem[16384];

    const int id = blockIdx.x;
    const int bz = id & 7;
    const int s  = id >> 3;
    const int bx = s & 3, by = s >> 2;
    const int n0 = bx * 128;
    const int m0 = by * 128;

    const unsigned short* Ahb = Ah + (size_t)bz * strideA;
    const unsigned short* Bhb = Bh + (size_t)bz * strideB;

    const int tid = threadIdx.x;
    const int lane = tid & 63;
    const int wv = tid >> 6;
    const int wr = wv >> 1, wc = wv & 1;
    const int l4 = lane >> 4, l15 = lane & 15;
    const int srow = lane >> 2, scol8 = (lane & 3) * 8;

    f32x4 acc[4][4] = {};

    for (int k0 = 0; k0 < K; k0 += 32) {
#pragma unroll
        for (int cc = 0; cc < 2; ++cc) {
            const int c = wv * 2 + cc;
            const size_t aoff = (size_t)(m0 + c * 16 + srow) * lda + k0 + scol8;
            const size_t boff = (size_t)(n0 + c * 16 + srow) * ldb + k0 + scol8;
            gload_lds16(Ahb + aoff, smem + c * 1024);
            gload_lds16(Bhb + boff, smem + 8192 + c * 1024);
        }
        __syncthreads();

        f16x8 ah[4], bh[4];
#pragma unroll
        for (int f = 0; f < 4; ++f) {
            const int arow = wr * 64 + f * 16 + l15;
            const int brow = wc * 64 + f * 16 + l15;
            ah[f] = *(const f16x8*)(smem + arow * 64 + l4 * 16);
            bh[f] = *(const f16x8*)(smem + 8192 + brow * 64 + l4 * 16);
        }
#pragma unroll
        for (int fm = 0; fm < 4; ++fm)
#pragma unroll
            for (int fn = 0; fn < 4; ++fn)
                acc[fm][fn] = __builtin_amdgcn_mfma_f32_16x16x32_f16(
                    ah[fm], bh[fn], acc[fm][fn], 0, 0, 0);
        __syncthreads();
    }

#pragma unroll
    for (int fm = 0; fm < 4; ++fm) {
#pragma unroll
        for (int fn = 0; fn < 4; ++fn) {
            const int m = m0 + wr * 64 + fm * 16 + l4 * 4;
            const int n = n0 + wc * 64 + fn * 16 + l15;
            unsigned short* H = (unsigned short*)C0 + (size_t)bz * strideC;
            const float sc = g[n] * rsqrtf(var[n] + EPSV);
            const float sh = bt[n] - mu[n] * sc;
            alignas(8) unsigned short h4[4];
#pragma unroll
            for (int r = 0; r < 4; ++r)
                h4[r] = f16b(acc[fm][fn][r] * sc + sh);
            *(ushort4*)&H[(size_t)n * M + m] = *(ushort4*)&h4[0];
        }
    }
}

// ---------------------------------------------------------------------------
// qk256<EPI>: 256x256 tile, BK=64, 8 waves (2Mx4N, per-wave 128x64),
// 128 KiB double-buffered LDS, counted vmcnt(8), T2 XOR swizzle (round-9
// involution verbatim), setprio around the 64-MFMA cluster.
// EPI_QK:    A=qT B=kT (stacked, lda/ldb=1024); epilogue exp/stats, scalar
//            p-stores, ML per-64-col tile (layout identical to round 9).
// EPI_PROJT: A=stacked Wqk (M=1024, strideA=0), B=xT; BN epilogue with
//            stacked params; fp16 out at [n*M+m].
// ---------------------------------------------------------------------------
constexpr int EPI_QK = 0, EPI_PROJT = 2;

template <int EPI>
__global__ __launch_bounds__(512, 2) void qk256(
    const unsigned short* __restrict__ Ah, const unsigned short* __restrict__ Bh,
    int M, int N, int K, int lda, int ldb,
    long strideA, long strideB, long strideC,
    void* __restrict__ C0, float* __restrict__ ML,
    const float* __restrict__ g, const float* __restrict__ bt,
    const float* __restrict__ mu, const float* __restrict__ var)
{
    __shared__ char smem[131072];          // 2 x (32KB A + 32KB B)

    const int id = blockIdx.x;
    const int bz = id & 7;                 // batch-pinned XCD
    const int s  = id >> 3;
    const int bx = s & 7, by = s >> 3;
    const int n0 = bx * 256;
    const int m0 = by * 256;

    const unsigned short* Ahb = Ah + (size_t)bz * strideA;
    const unsigned short* Bhb = Bh + (size_t)bz * strideB;

    const int tid  = threadIdx.x;
    const int lane = tid & 63;
    const int wv   = tid >> 6;
    const int wr   = wv >> 2, wc = wv & 3;
    const int WRB  = wr * 128, WCB = wc * 64;
    const int l4 = lane >> 4, l15 = lane & 15;

    const int srow  = tid >> 3;                       // 0..63
    const int sslot = ((tid & 7) ^ (srow & 7)) * 8;   // pre-swizzled col

#define STAGE(t)                                                              \
    {                                                                         \
        char* dst = smem + ((t) & 1) * 65536;                                 \
        const unsigned short* asrc =                                          \
            Ahb + (size_t)(m0 + srow) * lda + (t) * 64 + sslot;               \
        _Pragma("unroll")                                                     \
        for (int u = 0; u < 4; ++u)                                           \
            gload_lds16(asrc + (size_t)(u * 64) * lda,                        \
                        dst + u * 8192 + tid * 16);                           \
        const unsigned short* bsrc =                                          \
            Bhb + (size_t)(n0 + srow) * ldb + (t) * 64 + sslot;               \
        _Pragma("unroll")                                                     \
        for (int u = 0; u < 4; ++u)                                           \
            gload_lds16(bsrc + (size_t)(u * 64) * ldb,                        \
                        dst + 32768 + u * 8192 + tid * 16);                   \
    }

    f32x4 acc[8][4] = {};
    const int NT = K / 64;

    STAGE(0);

    for (int t = 0; t < NT; ++t) {
        char* cur = smem + (t & 1) * 65536;
        __builtin_amdgcn_s_barrier();          // buf[(t+1)&1] fully consumed
        if (t + 1 < NT) {
            STAGE(t + 1);
            asm volatile("s_waitcnt vmcnt(8)" ::: "memory");
        } else {
            asm volatile("s_waitcnt vmcnt(0)" ::: "memory");
        }
        __builtin_amdgcn_s_barrier();          // tile t staged by all waves

        f16x8 ah[8][2], bh[4][2];
#pragma unroll
        for (int m = 0; m < 8; ++m) {
            const int row = WRB + m * 16 + l15;
#pragma unroll
            for (int kk = 0; kk < 2; ++kk)
                ah[m][kk] = *(const f16x8*)(cur + row * 128 +
                                            (((kk << 2) | l4) ^ (row & 7)) * 16);
        }
#pragma unroll
        for (int n = 0; n < 4; ++n) {
            const int row = WCB + n * 16 + l15;
#pragma unroll
            for (int kk = 0; kk < 2; ++kk)
                bh[n][kk] = *(const f16x8*)(cur + 32768 + row * 128 +
                                            (((kk << 2) | l4) ^ (row & 7)) * 16);
        }
        __builtin_amdgcn_s_setprio(1);
#pragma unroll
        for (int kk = 0; kk < 2; ++kk)
#pragma unroll
            for (int m = 0; m < 8; ++m)
#pragma unroll
                for (int n = 0; n < 4; ++n)
                    acc[m][n] = __builtin_amdgcn_mfma_f32_16x16x32_f16(
                        ah[m][kk], bh[n][kk], acc[m][n], 0, 0, 0);
        __builtin_amdgcn_s_setprio(0);
    }
#undef STAGE

    if constexpr (EPI == EPI_QK) {
        unsigned short* H = (unsigned short*)C0 + (size_t)bz * strideC;
        const int tcol = bx * 4 + wc;                     // 64-col tile id
        const size_t mbase = (((size_t)bz * 32 + tcol) * 2) * 2048;
#pragma unroll
        for (int m = 0; m < 8; ++m) {
#pragma unroll
            for (int r = 0; r < 4; ++r) {
                float mx = fmaxf(fmaxf(acc[m][0][r], acc[m][1][r]),
                                 fmaxf(acc[m][2][r], acc[m][3][r]));
#pragma unroll
                for (int off = 1; off < 16; off <<= 1)
                    mx = fmaxf(mx, __shfl_xor(mx, off));
                float pe[4];
                float s2 = 0.f;
#pragma unroll
                for (int n = 0; n < 4; ++n) {
                    pe[n] = __expf(acc[m][n][r] - mx);
                    s2 += pe[n];
                }
#pragma unroll
                for (int off = 1; off < 16; off <<= 1)
                    s2 += __shfl_xor(s2, off);
                const int rloc = WRB + m * 16 + l4 * 4 + r;   // 0..255
                if (l15 == 0) {
                    ML[mbase + m0 + rloc] = mx;
                    ML[mbase + 2048 + m0 + rloc] = s2;
                }
#pragma unroll
                for (int n = 0; n < 4; ++n)
                    H[(size_t)(m0 + rloc) * 2048 + n0 + WCB + n * 16 + l15] =
                        f16b(pe[n]);
            }
        }
    } else {  // EPI_PROJT (stacked BN by m)
        unsigned short* H = (unsigned short*)C0 + (size_t)bz * strideC;
#pragma unroll
        for (int m = 0; m < 8; ++m) {
            const int mg = m0 + WRB + m * 16 + l4 * 4;
            float sc[4], sh[4];
#pragma unroll
            for (int r = 0; r < 4; ++r) {
                const int o = mg + r;
                sc[r] = g[o] * rsqrtf(var[o] + EPSV);
                sh[r] = bt[o] - mu[o] * sc[r];
            }
#pragma unroll
            for (int n = 0; n < 4; ++n) {
                const int ng = n0 + WCB + n * 16 + l15;
                alignas(8) unsigned short h4[4];
#pragma unroll
                for (int r = 0; r < 4; ++r)
                    h4[r] = f16b(acc[m][n][r] * sc[r] + sh[r]);
                *(ushort4*)&H[(size_t)ng * M + mg] = *(ushort4*)&h4[0];
            }
        }
    }
}

// ---------------------------------------------------------------------------
// PV: 256x128, tri-buffered, counted vmcnt(6) — round-9 code verbatim.
// ---------------------------------------------------------------------------
__global__ __launch_bounds__(512, 2) void pv256(
    const unsigned short* __restrict__ Ah, const unsigned short* __restrict__ Bh,
    int K, int lda, int ldb, long strideA, long strideB, long strideC,
    void* __restrict__ C0,
    const float* __restrict__ corr, const float* __restrict__ linv)
{
    constexpr int BUFSZ = 49152;
    __shared__ char smem[163840];

    const int id = blockIdx.x;
    const int bz = id & 7;
    const int s  = id >> 3;
    const int bx = s & 3, by = s >> 2;
    const int n0 = bx * 128;
    const int m0 = by * 256;

    const unsigned short* Ahb = Ah + (size_t)bz * strideA;
    const unsigned short* Bhb = Bh + (size_t)bz * strideB;

    const int tid  = threadIdx.x;
    const int lane = tid & 63;
    const int wv   = tid >> 6;
    const int wr   = wv >> 2, wc = wv & 3;
    const int WRB  = wr * 128, WCB = wc * 32;
    const int l4 = lane >> 4, l15 = lane & 15;

    const int srow = tid >> 3;
    const int sslot = ((tid & 7) ^ (srow & 7)) * 8;

    unsigned short* corrLds = (unsigned short*)(smem + 147456);
    for (int idx = tid; idx < 2048; idx += 512) {
        const int t = idx >> 6, i4 = (idx & 63) * 4;
        float4 c4 = *(const float4*)&corr[((size_t)bz * 32 + t) * 2048 + m0 + i4];
        alignas(8) unsigned short h4[4] =
            {f16b(c4.x), f16b(c4.y), f16b(c4.z), f16b(c4.w)};
        *(ushort4*)&corrLds[(size_t)t * 256 + i4] = *(ushort4*)&h4[0];
    }
    __syncthreads();

#define STAGE(t)                                                              \
    {                                                                         \
        char* dst = smem + ((t) % 3) * BUFSZ;                                 \
        const unsigned short* asrc =                                          \
            Ahb + (size_t)(m0 + srow) * lda + (t) * 64 + sslot;               \
        _Pragma("unroll")                                                     \
        for (int u = 0; u < 4; ++u)                                           \
            gload_lds16(asrc + (size_t)(u * 64) * lda,                        \
                        dst + u * 8192 + tid * 16);                           \
        const unsigned short* bsrc =                                          \
            Bhb + (size_t)(n0 + srow) * ldb + (t) * 64 + sslot;               \
        _Pragma("unroll")                                                     \
        for (int u = 0; u < 2; ++u)                                           \
            gload_lds16(bsrc + (size_t)(u * 64) * ldb,                        \
                        dst + 32768 + u * 8192 + tid * 16);                   \
    }

    f32x4 acc[8][2] = {};
    const int NT = K / 64;

    STAGE(0);
    STAGE(1);

    for (int t = 0; t < NT; ++t) {
        char* cur = smem + (t % 3) * BUFSZ;
        if (t + 2 < NT) {
            asm volatile("s_waitcnt vmcnt(6)" ::: "memory");
        } else {
            asm volatile("s_waitcnt vmcnt(0)" ::: "memory");
        }
        __builtin_amdgcn_s_barrier();
        asm volatile("" ::: "memory");
        if (t + 2 < NT) STAGE(t + 2);

        f16x8 ah[8][2], bh[2][2];
#pragma unroll
        for (int m = 0; m < 8; ++m) {
            const int row = WRB + m * 16 + l15;
#pragma unroll
            for (int kk = 0; kk < 2; ++kk)
                ah[m][kk] = *(const f16x8*)(cur + row * 128 +
                                            (((kk << 2) | l4) ^ (row & 7)) * 16);
        }
#pragma unroll
        for (int n = 0; n < 2; ++n) {
            const int row = WCB + n * 16 + l15;
#pragma unroll
            for (int kk = 0; kk < 2; ++kk)
                bh[n][kk] = *(const f16x8*)(cur + 32768 + row * 128 +
                                            (((kk << 2) | l4) ^ (row & 7)) * 16);
        }
#pragma unroll
        for (int m = 0; m < 8; ++m) {
            const _Float16 cf = ((const _Float16*)corrLds)
                [(size_t)t * 256 + WRB + m * 16 + l15];
            ah[m][0] = ah[m][0] * cf;
            ah[m][1] = ah[m][1] * cf;
        }
        __builtin_amdgcn_s_setprio(1);
#pragma unroll
        for (int kk = 0; kk < 2; ++kk)
#pragma unroll
            for (int m = 0; m < 8; ++m)
#pragma unroll
                for (int n = 0; n < 2; ++n)
                    acc[m][n] = __builtin_amdgcn_mfma_f32_16x16x32_f16(
                        ah[m][kk], bh[n][kk], acc[m][n], 0, 0, 0);
        __builtin_amdgcn_s_setprio(0);
    }
#undef STAGE

    float* Cb = (float*)C0 + (size_t)bz * strideC;
    const float* lb = linv + (size_t)bz * 2048;
#pragma unroll
    for (int m = 0; m < 8; ++m) {
        const int mrow = m0 + WRB + m * 16 + l4 * 4;
        float lv[4];
#pragma unroll
        for (int r = 0; r < 4; ++r)
            lv[r] = lb[mrow + r];
#pragma unroll
        for (int n = 0; n < 2; ++n) {
            const int col = n0 + WCB + n * 16 + l15;
            float4 o4 = make_float4(acc[m][n][0] * lv[0],
                                    acc[m][n][1] * lv[1],
                                    acc[m][n][2] * lv[2],
                                    acc[m][n][3] * lv[3]);
            *(float4*)&Cb[(size_t)col * 2048 + mrow] = o4;
        }
    }
}

// ---------------------------------------------------------------------------
__global__ __launch_bounds__(256) void ml_combine_kernel(
    const float* __restrict__ ml, float* __restrict__ corr,
    float* __restrict__ linv)
{
    const int idx = blockIdx.x * 256 + threadIdx.x;
    const int b = idx >> 11, i = idx & 2047;
    const float* base = ml + ((size_t)b * 32) * 2 * 2048 + i;
    float M = -3.0e38f;
#pragma unroll 8
    for (int t = 0; t < 32; ++t)
        M = fmaxf(M, base[(size_t)t * 4096]);
    float L = 0.f;
    float* cb = corr + (size_t)b * 32 * 2048 + i;
#pragma unroll 8
    for (int t = 0; t < 32; ++t) {
        const float c = __expf(base[(size_t)t * 4096] - M);
        L += c * base[(size_t)t * 4096 + 2048];
        cb[(size_t)t * 2048] = c;
    }
    linv[idx] = 1.0f / L;
}

// ---------------------------------------------------------------------------
extern "C" void kernel_launch(void* const* d_in, const int* in_sizes, int n_in,
                              void* d_out, int out_size, void* d_ws, size_t ws_size,
                              hipStream_t stream)
{
    (void)in_sizes; (void)n_in; (void)out_size; (void)ws_size;
    const float* x  = (const float*)d_in[0];
    const float* Wq = (const float*)d_in[1];
    const float* gq = (const float*)d_in[2];
    const float* bq = (const float*)d_in[3];
    const float* mq = (const float*)d_in[4];
    const float* vq = (const float*)d_in[5];
    const float* Wk = (const float*)d_in[6];
    const float* gk = (const float*)d_in[7];
    const float* bk = (const float*)d_in[8];
    const float* mk = (const float*)d_in[9];
    const float* vk = (const float*)d_in[10];
    const float* Wv = (const float*)d_in[11];
    const float* gv = (const float*)d_in[12];
    const float* bv = (const float*)d_in[13];
    const float* mv = (const float*)d_in[14];
    const float* vv = (const float*)d_in[15];
    float* out = (float*)d_out;

    const size_t MiB = 1048576;
    char* ws = (char*)d_ws;
    unsigned short* Wqh = (unsigned short*)(ws + 0 * 524288);   // stacked with
    unsigned short* Wkh = (unsigned short*)(ws + 1 * 524288);   //  Wk below it
    unsigned short* Wvh = (unsigned short*)(ws + 2 * 524288);
    unsigned short* vbf  = (unsigned short*)(ws + 2 * MiB);     // 16 MiB (d,j)
    unsigned short* qkTh = (unsigned short*)(ws + 18 * MiB);    // 32 MiB (n,[q|k])
    unsigned short* xTh  = (unsigned short*)(ws + 50 * MiB);    // 16 MiB (n,c)
    unsigned short* pbuf = (unsigned short*)(ws + 66 * MiB);    // 64 MiB fp16 p
    float* mlbuf = (float*)(ws + 130 * MiB);                    // 4 MiB stats
    float* corr  = (float*)(ws + 134 * MiB);                    // 2 MiB
    float* linv  = (float*)(ws + 136 * MiB);                    // 64 KiB
    float* sg = (float*)(ws + 136 * MiB + 65536);               // 4 KiB each
    float* sb = sg + 1024;
    float* sm = sb + 1024;
    float* sv = sm + 1024;

    const long BS = (long)N_ * C_;              // 1M elems per batch
    const long QKS = (long)N_ * 1024;           // stacked qk per batch

    // --- conversions + param concat ---
    split_x_kernel<<<dim3(N_ / 64, C_ / 64, B_), 256, 0, stream>>>(x, xTh);
    split_w_kernel<<<dim3(256), 256, 0, stream>>>(Wq, Wqh);
    split_w_kernel<<<dim3(256), 256, 0, stream>>>(Wk, Wkh);
    split_w_kernel<<<dim3(256), 256, 0, stream>>>(Wv, Wvh);
    param_concat_kernel<<<dim3(1), 512, 0, stream>>>(
        gq, bq, mq, vq, gk, bk, mk, vk, sg, sb, sm, sv);

    // --- stacked q/k projection: M=1024 (Wq rows then Wk rows) ---
    qk256<EPI_PROJT><<<dim3(256), 512, 0, stream>>>(
        Wqh, xTh, 1024, 2048, 512, 512, 512, 0, BS, QKS, qkTh,
        nullptr, sg, sb, sm, sv);

    // --- v projection (128² m97) ---
    projv_mfma<<<dim3(512), 256, 0, stream>>>(
        xTh, Wvh, 2048, 512, 512, 512, 512, BS, 0, BS, vbf,
        gv, bv, mv, vv);

    // --- logits -> p_local fp16 + per-tile stats (256², counted vmcnt) ---
    qk256<EPI_QK><<<dim3(512), 512, 0, stream>>>(
        qkTh, qkTh + 512, 2048, 2048, 512, 1024, 1024, QKS, QKS,
        (long)N_ * N_, pbuf, mlbuf, nullptr, nullptr, nullptr, nullptr);

    // --- combine stats -> corr, linv ---
    ml_combine_kernel<<<dim3(B_ * N_ / 256), 256, 0, stream>>>(
        mlbuf, corr, linv);

    // --- PV (256x128, tri-buffer counted vmcnt, corr-scaled, /l epilogue) ---
    pv256<<<dim3(256), 512, 0, stream>>>(
        pbuf, vbf, 2048, 2048, 2048, (long)N_ * N_, BS, BS, out, corr, linv);
}